// Round 10
// baseline (150.258 us; speedup 1.0000x reference)
//
#include <hip/hip_runtime.h>

// 2-layer GCN, rank-2 factorization + 2-level (dst,src)-range bucketing + LDS
// aggregation. R10: consolidation round —
//  - cnt stored in both layouts; bscatter loads h coalesced (no recount)
//  - bscatter lofs via block-scan (was serial thread-0 loop)
//  - last-block fusion (threadfence+done counter): scanB into scanA,
//    px into deg, node-MLP into agg1, out into agg2.  10 -> 6 kernels.

#define NBMAX 1024
#define NRMAX 32
#define AGG_BLKS 8
#define CHUNK 4096
#define NCHP 640         // max chunks (e <= 2.62M edges)
#define DBITS 12
#define DMASK 4095
#define NOEDGE 0xFFFFFFFFu

// ---------------- block-wide exclusive scan (1024 threads) ----------------

__device__ __forceinline__ int block_scan_excl(int v, int tid, int* wtot /*LDS[17]*/) {
    int lane = tid & 63, w = tid >> 6;
    int inc = v;
#pragma unroll
    for (int d = 1; d < 64; d <<= 1) {
        int u = __shfl_up(inc, d);
        if (lane >= d) inc += u;
    }
    if (lane == 63) wtot[w] = inc;
    __syncthreads();
    if (w == 0) {
        int t = (lane < 16) ? wtot[lane] : 0;
#pragma unroll
        for (int d = 1; d < 16; d <<= 1) {
            int u = __shfl_up(t, d);
            if (lane >= d) t += u;
        }
        if (lane < 16) wtot[lane] = t;
        if (lane == 15) wtot[16] = t;   // grand total
    }
    __syncthreads();
    int base = (w > 0) ? wtot[w - 1] : 0;
    return base + inc - v;   // exclusive
}

// ---------------- bucketing: count -> scan(A+B) -> scatter ------------

__global__ void k_cnt(const int* __restrict__ src, const int* __restrict__ dst,
                      int* __restrict__ cnt, int* __restrict__ cntT,
                      int e, int NS, int NB) {
    __shared__ int h[NBMAX];
    for (int t = threadIdx.x; t < NB; t += blockDim.x) h[t] = 0;
    __syncthreads();
    int c0 = blockIdx.x * CHUNK, c1 = min(c0 + CHUNK, e);
    int len = c1 - c0, lq = len >> 2;
    const int4* d4 = (const int4*)(dst + c0);
    const int4* s4 = (const int4*)(src + c0);
    for (int j = threadIdx.x; j < lq; j += blockDim.x) {
        int4 dv = d4[j], sv = s4[j];
        atomicAdd(&h[(dv.x >> DBITS) * NS + (sv.x >> DBITS)], 1);
        atomicAdd(&h[(dv.y >> DBITS) * NS + (sv.y >> DBITS)], 1);
        atomicAdd(&h[(dv.z >> DBITS) * NS + (sv.z >> DBITS)], 1);
        atomicAdd(&h[(dv.w >> DBITS) * NS + (sv.w >> DBITS)], 1);
    }
    if (threadIdx.x == 0)
        for (int i = lq * 4; i < len; ++i)
            atomicAdd(&h[(dst[c0 + i] >> DBITS) * NS + (src[c0 + i] >> DBITS)], 1);
    __syncthreads();
    for (int t = threadIdx.x; t < NB; t += blockDim.x) {
        int v = h[t];
        cnt[t * NCHP + blockIdx.x] = v;          // bin-major (scanA reads rows)
        cntT[blockIdx.x * NBMAX + t] = v;        // chunk-major (bscatter coalesced)
    }
}

// one block PER BIN: scan of chunk counts; LAST block also does the bin-base
// scan (scanB), region table, and sentinel fill.
__global__ __launch_bounds__(1024)
void k_scanA(const int* __restrict__ cnt, int* __restrict__ ofs,
             int* __restrict__ tot, int* __restrict__ doneA,
             int* __restrict__ gbin, int* __restrict__ rbase, int* __restrict__ rlenp,
             unsigned* __restrict__ packed, int NB, int NS, int NCH) {
    __shared__ int wtot[17];
    __shared__ int lastflag;
    int bin = blockIdx.x, tid = threadIdx.x;
    int v = (tid < NCH) ? cnt[bin * NCHP + tid] : 0;
    int ex = block_scan_excl(v, tid, wtot);
    if (tid < NCH) ofs[bin * NCHP + tid] = ex;
    if (tid == 0) tot[bin] = wtot[16];
    __syncthreads();   // drain stores (compiler emits vmcnt(0) before barrier)
    if (tid == 0) {
        __threadfence();
        lastflag = (atomicAdd(doneA, 1) == (int)gridDim.x - 1) ? 1 : 0;
    }
    __syncthreads();
    if (!lastflag) return;
    // ---- scanB (runs in the last-finishing block) ----
    int t = (tid < NB) ? tot[tid] : 0;
    int p = (t + 3) & ~3;
    __syncthreads();
    int gb = block_scan_excl(p, tid, wtot);
    int totalp = wtot[16];
    if (tid < NB) {
        gbin[tid] = gb;
        for (int k = t; k < p; ++k) packed[gb + k] = NOEDGE;  // pad sentinels
    }
    __syncthreads();
    if (tid < NB && (tid % NS) == 0) {
        int r = tid / NS;
        rbase[r] = gb;
        int nxt = (tid + NS < NB) ? gbin[tid + NS] : totalp;
        rlenp[r] = nxt - gb;   // multiple of 4
    }
}

// LDS counting-sort per chunk into 2-level bins; h loaded from cntT (no
// recount); lofs via block-scan; sorted-order flush.
__global__ __launch_bounds__(1024)
void k_bscatter(const int* __restrict__ src, const int* __restrict__ dst,
                const int* __restrict__ cntT, const int* __restrict__ ofs,
                const int* __restrict__ gbin, unsigned* __restrict__ packed,
                int e, int NS, int NB) {
    __shared__ int lofs[NBMAX], curx[NBMAX], gb[NBMAX];
    __shared__ unsigned sbuf[CHUNK];   // 16 KB
    __shared__ int dest[CHUNK];        // 16 KB
    __shared__ int wtot[17];
    int blk = blockIdx.x, tid = threadIdx.x;
    int c0 = blk * CHUNK, c1 = min(c0 + CHUNK, e);
    int len = c1 - c0, lq = len >> 2;
    int hv = (tid < NB) ? cntT[blk * NBMAX + tid] : 0;
    int lo = block_scan_excl(hv, tid, wtot);
    if (tid < NB) {
        lofs[tid] = lo;
        curx[tid] = lo;
        gb[tid] = gbin[tid] + ofs[tid * NCHP + blk] - lo;  // dest = gb[b] + slot
    }
    __syncthreads();
    const int4* d4 = (const int4*)(dst + c0);
    const int4* s4 = (const int4*)(src + c0);
    // place into LDS sorted by bin; record global dest per slot
    for (int j = tid; j < lq; j += blockDim.x) {
        int4 dv = d4[j], sv = s4[j];
        {
            int b = (dv.x >> DBITS) * NS + (sv.x >> DBITS);
            int sl = atomicAdd(&curx[b], 1);
            sbuf[sl] = ((unsigned)sv.x << DBITS) | (unsigned)(dv.x & DMASK);
            dest[sl] = gb[b] + sl;
        }
        {
            int b = (dv.y >> DBITS) * NS + (sv.y >> DBITS);
            int sl = atomicAdd(&curx[b], 1);
            sbuf[sl] = ((unsigned)sv.y << DBITS) | (unsigned)(dv.y & DMASK);
            dest[sl] = gb[b] + sl;
        }
        {
            int b = (dv.z >> DBITS) * NS + (sv.z >> DBITS);
            int sl = atomicAdd(&curx[b], 1);
            sbuf[sl] = ((unsigned)sv.z << DBITS) | (unsigned)(dv.z & DMASK);
            dest[sl] = gb[b] + sl;
        }
        {
            int b = (dv.w >> DBITS) * NS + (sv.w >> DBITS);
            int sl = atomicAdd(&curx[b], 1);
            sbuf[sl] = ((unsigned)sv.w << DBITS) | (unsigned)(dv.w & DMASK);
            dest[sl] = gb[b] + sl;
        }
    }
    if (tid == 0)
        for (int i = lq * 4; i < len; ++i) {
            int d = dst[c0 + i], sx = src[c0 + i];
            int b = (d >> DBITS) * NS + (sx >> DBITS);
            int sl = atomicAdd(&curx[b], 1);
            sbuf[sl] = ((unsigned)sx << DBITS) | (unsigned)(d & DMASK);
            dest[sl] = gb[b] + sl;
        }
    __syncthreads();
    for (int t = tid; t < len; t += blockDim.x)
        packed[dest[t]] = sbuf[t];
}

// ---------------- LDS aggregations -> partials; last block per range fuses
// the node-local consumer (px / node-MLP / out) ----------------

__global__ __launch_bounds__(1024, 8)
void k_degpx(const unsigned* __restrict__ packed, const int* __restrict__ rbase,
             const int* __restrict__ rlenp, int* __restrict__ pdeg,
             int* __restrict__ done_deg, const float2* __restrict__ x,
             float* __restrict__ dinv, float2* __restrict__ px, int n) {
    __shared__ int acc[DMASK + 1];   // 16 KB
    __shared__ int lastflag;
    int r = blockIdx.y, b = blockIdx.x, tid = threadIdx.x;
    int rs_r = min(DMASK + 1, n - (r << DBITS));
    for (int t = tid; t < rs_r; t += blockDim.x) acc[t] = 0;
    __syncthreads();
    int base = rbase[r], q = rlenp[r] >> 2;
    int qper = (q + AGG_BLKS - 1) / AGG_BLKS;
    int qlo = b * qper, qhi = min(qlo + qper, q);
    const uint4* p4 = (const uint4*)(packed + base);
    for (int j = qlo + tid; j < qhi; j += blockDim.x) {
        uint4 v = p4[j];
        if (v.x != NOEDGE) atomicAdd(&acc[v.x & DMASK], 1);
        if (v.y != NOEDGE) atomicAdd(&acc[v.y & DMASK], 1);
        if (v.z != NOEDGE) atomicAdd(&acc[v.z & DMASK], 1);
        if (v.w != NOEDGE) atomicAdd(&acc[v.w & DMASK], 1);
    }
    __syncthreads();
    int nb = b * n + (r << DBITS);
    for (int t = tid; t < rs_r; t += blockDim.x) pdeg[nb + t] = acc[t];
    __syncthreads();
    if (tid == 0) {
        __threadfence();
        lastflag = (atomicAdd(&done_deg[r], 1) == (int)gridDim.x - 1) ? 1 : 0;
    }
    __syncthreads();
    if (!lastflag) return;
    // fused px for this range
    int nbase = r << DBITS;
    for (int t = tid; t < rs_r; t += blockDim.x) {
        int i = nbase + t;
        int deg = 1;
#pragma unroll
        for (int bb = 0; bb < AGG_BLKS; ++bb) deg += pdeg[bb * n + i];
        float d = rsqrtf((float)deg);
        dinv[i] = d;
        float2 xv = x[i];
        px[i] = make_float2(d * xv.x, d * xv.y);
    }
}

__global__ __launch_bounds__(1024, 4)
void k_agg1n(const unsigned* __restrict__ packed, const int* __restrict__ rbase,
             const int* __restrict__ rlenp, const float2* __restrict__ px,
             float2* __restrict__ pP, int* __restrict__ done_a1,
             const float* __restrict__ dinv, const float* __restrict__ W1,
             const float* __restrict__ b1, const float* __restrict__ W2,
             float* __restrict__ s, int n) {
    __shared__ float acc[2 * (DMASK + 1)];   // 32 KB
    __shared__ int lastflag;
    int r = blockIdx.y, b = blockIdx.x, tid = threadIdx.x;
    int rs_r = min(DMASK + 1, n - (r << DBITS));
    for (int t = tid; t < 2 * rs_r; t += blockDim.x) acc[t] = 0.f;
    __syncthreads();
    int base = rbase[r], q = rlenp[r] >> 2;
    int qper = (q + AGG_BLKS - 1) / AGG_BLKS;
    int qlo = b * qper, qhi = min(qlo + qper, q);
    const uint4* p4 = (const uint4*)(packed + base);
    int nm1 = n - 1;
    for (int j = qlo + tid; j < qhi; j += blockDim.x) {
        uint4 v = p4[j];
        int i0 = min((int)(v.x >> DBITS), nm1);   // sentinel-safe clamp
        int i1 = min((int)(v.y >> DBITS), nm1);
        int i2 = min((int)(v.z >> DBITS), nm1);
        int i3 = min((int)(v.w >> DBITS), nm1);
        float2 g0 = px[i0], g1 = px[i1], g2 = px[i2], g3 = px[i3];
        if (v.x != NOEDGE) { int d0 = (v.x & DMASK) * 2; atomicAdd(&acc[d0], g0.x); atomicAdd(&acc[d0 + 1], g0.y); }
        if (v.y != NOEDGE) { int d1 = (v.y & DMASK) * 2; atomicAdd(&acc[d1], g1.x); atomicAdd(&acc[d1 + 1], g1.y); }
        if (v.z != NOEDGE) { int d2 = (v.z & DMASK) * 2; atomicAdd(&acc[d2], g2.x); atomicAdd(&acc[d2 + 1], g2.y); }
        if (v.w != NOEDGE) { int d3 = (v.w & DMASK) * 2; atomicAdd(&acc[d3], g3.x); atomicAdd(&acc[d3 + 1], g3.y); }
    }
    __syncthreads();
    int nb = b * n + (r << DBITS);
    for (int t = tid; t < rs_r; t += blockDim.x)
        pP[nb + t] = make_float2(acc[2 * t], acc[2 * t + 1]);
    __syncthreads();
    if (tid == 0) {
        __threadfence();
        lastflag = (atomicAdd(&done_a1[r], 1) == (int)gridDim.x - 1) ? 1 : 0;
    }
    __syncthreads();
    if (!lastflag) return;
    // fused node MLP for this range
    int nbase = r << DBITS;
    for (int t = tid; t < rs_r; t += blockDim.x) {
        int i = nbase + t;
        float2 v = px[i];
        float ax = v.x, ay = v.y;
#pragma unroll
        for (int bb = 0; bb < AGG_BLKS; ++bb) {
            float2 p = pP[bb * n + i];
            ax += p.x; ay += p.y;
        }
        float d = dinv[i];
        float dot = 0.f;
#pragma unroll
        for (int j = 0; j < 32; ++j) {
            float a2 = fmaf(ax, W1[j], ay * W1[32 + j]);
            float hh = fmaxf(fmaf(d, a2, b1[j]), 0.f);
            dot = fmaf(hh, W2[j], dot);
        }
        s[i] = d * dot;
    }
}

__global__ __launch_bounds__(1024, 8)
void k_agg2o(const unsigned* __restrict__ packed, const int* __restrict__ rbase,
             const int* __restrict__ rlenp, const float* __restrict__ s,
             float* __restrict__ ps, int* __restrict__ done_a2,
             const float* __restrict__ dinv, const float* __restrict__ b2,
             float* __restrict__ out, int n) {
    __shared__ float acc[DMASK + 1];   // 16 KB
    __shared__ int lastflag;
    int r = blockIdx.y, b = blockIdx.x, tid = threadIdx.x;
    int rs_r = min(DMASK + 1, n - (r << DBITS));
    for (int t = tid; t < rs_r; t += blockDim.x) acc[t] = 0.f;
    __syncthreads();
    int base = rbase[r], q = rlenp[r] >> 2;
    int qper = (q + AGG_BLKS - 1) / AGG_BLKS;
    int qlo = b * qper, qhi = min(qlo + qper, q);
    const uint4* p4 = (const uint4*)(packed + base);
    int nm1 = n - 1;
    for (int j = qlo + tid; j < qhi; j += blockDim.x) {
        uint4 v = p4[j];
        int i0 = min((int)(v.x >> DBITS), nm1);
        int i1 = min((int)(v.y >> DBITS), nm1);
        int i2 = min((int)(v.z >> DBITS), nm1);
        int i3 = min((int)(v.w >> DBITS), nm1);
        float g0 = s[i0], g1 = s[i1], g2 = s[i2], g3 = s[i3];
        if (v.x != NOEDGE) atomicAdd(&acc[v.x & DMASK], g0);
        if (v.y != NOEDGE) atomicAdd(&acc[v.y & DMASK], g1);
        if (v.z != NOEDGE) atomicAdd(&acc[v.z & DMASK], g2);
        if (v.w != NOEDGE) atomicAdd(&acc[v.w & DMASK], g3);
    }
    __syncthreads();
    int nb = b * n + (r << DBITS);
    for (int t = tid; t < rs_r; t += blockDim.x) ps[nb + t] = acc[t];
    __syncthreads();
    if (tid == 0) {
        __threadfence();
        lastflag = (atomicAdd(&done_a2[r], 1) == (int)gridDim.x - 1) ? 1 : 0;
    }
    __syncthreads();
    if (!lastflag) return;
    // fused output for this range
    int nbase = r << DBITS;
    float bias = b2[0];
    for (int t = tid; t < rs_r; t += blockDim.x) {
        int i = nbase + t;
        float a2 = s[i];   // self-loop
#pragma unroll
        for (int bb = 0; bb < AGG_BLKS; ++bb) a2 += ps[bb * n + i];
        out[i] = dinv[i] * a2 + bias;
    }
}

// ---------------- fallback path (round-2 style) ----------------

__global__ void f_zero(int* __restrict__ ideg, float2* __restrict__ P, int n) {
    int i = blockIdx.x * blockDim.x + threadIdx.x;
    if (i < n) { ideg[i] = 0; P[i] = make_float2(0.f, 0.f); }
}
__global__ void f_count(const int* __restrict__ dst, int* __restrict__ ideg, int e) {
    int i = blockIdx.x * blockDim.x + threadIdx.x;
    if (i < e) atomicAdd(&ideg[dst[i]], 1);
}
__global__ void f_px(const float2* __restrict__ x, const int* __restrict__ ideg,
                     float* __restrict__ dinv, float2* __restrict__ px, int n) {
    int i = blockIdx.x * blockDim.x + threadIdx.x;
    if (i >= n) return;
    float d = rsqrtf((float)(1 + ideg[i]));
    dinv[i] = d;
    float2 xv = x[i];
    px[i] = make_float2(d * xv.x, d * xv.y);
}
__global__ void f_scatter_px(const int* __restrict__ src, const int* __restrict__ dst,
                             const float2* __restrict__ px, float* __restrict__ Pf, int e) {
    int i = blockIdx.x * blockDim.x + threadIdx.x;
    if (i >= e) return;
    int sidx = src[i], d = dst[i];
    float2 v = px[sidx];
    atomicAdd(&Pf[2 * d], v.x);
    atomicAdd(&Pf[2 * d + 1], v.y);
}
__global__ void f_node(const float2* __restrict__ px, const float2* __restrict__ P,
                       const float* __restrict__ dinv,
                       const float* __restrict__ W1, const float* __restrict__ b1,
                       const float* __restrict__ W2,
                       float* __restrict__ s, float* __restrict__ S, int n) {
    int i = blockIdx.x * blockDim.x + threadIdx.x;
    if (i >= n) return;
    float d = dinv[i];
    float2 v = px[i], p = P[i];
    float ax = v.x + p.x, ay = v.y + p.y;
    float dot = 0.f;
#pragma unroll
    for (int j = 0; j < 32; ++j) {
        float acc = fmaf(ax, W1[j], ay * W1[32 + j]);
        float h = fmaxf(fmaf(d, acc, b1[j]), 0.f);
        dot = fmaf(h, W2[j], dot);
    }
    float sv = d * dot;
    s[i] = sv;
    S[i] = sv;
}
__global__ void f_scatter_s(const int* __restrict__ src, const int* __restrict__ dst,
                            const float* __restrict__ s, float* __restrict__ S, int e) {
    int i = blockIdx.x * blockDim.x + threadIdx.x;
    if (i < e) atomicAdd(&S[dst[i]], s[src[i]]);
}
__global__ void f_out(const float* __restrict__ S, const float* __restrict__ dinv,
                      const float* __restrict__ b2, float* __restrict__ out, int n) {
    int i = blockIdx.x * blockDim.x + threadIdx.x;
    if (i < n) out[i] = dinv[i] * S[i] + b2[0];
}

// ---------------- launch ----------------

extern "C" void kernel_launch(void* const* d_in, const int* in_sizes, int n_in,
                              void* d_out, int out_size, void* d_ws, size_t ws_size,
                              hipStream_t stream) {
    const float* x  = (const float*)d_in[0];
    const int*   ei = (const int*)d_in[1];
    const float* W1 = (const float*)d_in[2];
    const float* b1 = (const float*)d_in[3];
    const float* W2 = (const float*)d_in[4];
    const float* b2 = (const float*)d_in[5];
    float* out = (float*)d_out;

    int n = in_sizes[0] / 2;   // 100000
    int e = in_sizes[1] / 2;   // 2560000
    const int* src = ei;
    const int* dst = ei + e;
    int NR  = (n + DMASK) >> DBITS;          // 25
    int NS  = NR;                            // src ranges (same granularity)
    int NB  = NR * NS;                       // 625 bins
    int NCH = (e + CHUNK - 1) / CHUNK;       // 625 chunks

    char* ws = (char*)d_ws;
    auto align = [](size_t v) { return (v + 255) & ~(size_t)255; };
    size_t off = 0;
    float*  dinv = (float*) (ws + off); off = align(off + (size_t)n * 4);
    float2* px   = (float2*)(ws + off); off = align(off + (size_t)n * 8);
    float*  s    = (float*) (ws + off); off = align(off + (size_t)n * 4);
    int*    pdeg = (int*)   (ws + off); off = align(off + (size_t)AGG_BLKS * n * 4);
    float2* pP   = (float2*)(ws + off); off = align(off + (size_t)AGG_BLKS * n * 8);
    float*  ps   = (float*) (ws + off); off = align(off + (size_t)AGG_BLKS * n * 4);
    int*    rbase = (int*)(ws + off); off = align(off + NRMAX * 4);
    int*    rlenp = (int*)(ws + off); off = align(off + NRMAX * 4);
    int*    gbin  = (int*)(ws + off); off = align(off + NBMAX * 4);
    int*    tot   = (int*)(ws + off); off = align(off + NBMAX * 4);
    int*    ctrl  = (int*)(ws + off); off = align(off + 512);
    int*    doneA    = ctrl;
    int*    done_deg = ctrl + 16;
    int*    done_a1  = ctrl + 16 + NRMAX;
    int*    done_a2  = ctrl + 16 + 2 * NRMAX;
    int*    cnt   = (int*)(ws + off); off = align(off + (size_t)NBMAX * NCHP * 4);
    int*    cntT  = (int*)(ws + off); off = align(off + (size_t)NCHP * NBMAX * 4);
    int*    ofs   = (int*)(ws + off); off = align(off + (size_t)NBMAX * NCHP * 4);
    unsigned* packed = (unsigned*)(ws + off);
    size_t need = off + (size_t)(e + 4 * NBMAX) * 4;

    const int B = 256;
    int gn = (n + B - 1) / B, ge = (e + B - 1) / B;

    bool fast = (need <= ws_size) && (NB <= NBMAX) && (NCH <= NCHP) && (NR <= NRMAX);

    if (fast) {
        dim3 ag(AGG_BLKS, NR);
        hipMemsetAsync(ctrl, 0, 512, stream);
        k_cnt     <<<NCH, B, 0, stream>>>(src, dst, cnt, cntT, e, NS, NB);
        k_scanA   <<<NB, 1024, 0, stream>>>(cnt, ofs, tot, doneA, gbin, rbase, rlenp,
                                            packed, NB, NS, NCH);
        k_bscatter<<<NCH, 1024, 0, stream>>>(src, dst, cntT, ofs, gbin, packed, e, NS, NB);
        k_degpx   <<<ag, 1024, 0, stream>>>(packed, rbase, rlenp, pdeg, done_deg,
                                            (const float2*)x, dinv, px, n);
        k_agg1n   <<<ag, 1024, 0, stream>>>(packed, rbase, rlenp, px, pP, done_a1,
                                            dinv, W1, b1, W2, s, n);
        k_agg2o   <<<ag, 1024, 0, stream>>>(packed, rbase, rlenp, s, ps, done_a2,
                                            dinv, b2, out, n);
    } else {
        int*   ideg = pdeg;
        float2* P   = pP;
        float* S    = ps;
        f_zero      <<<gn, B, 0, stream>>>(ideg, P, n);
        f_count     <<<ge, B, 0, stream>>>(dst, ideg, e);
        f_px        <<<gn, B, 0, stream>>>((const float2*)x, ideg, dinv, px, n);
        f_scatter_px<<<ge, B, 0, stream>>>(src, dst, px, (float*)P, e);
        f_node      <<<gn, B, 0, stream>>>(px, P, dinv, W1, b1, W2, s, S, n);
        f_scatter_s <<<ge, B, 0, stream>>>(src, dst, s, S, e);
        f_out       <<<gn, B, 0, stream>>>(S, dinv, b2, out, n);
    }
}

// Round 11
// 110.240 us; speedup vs baseline: 1.3630x; 1.3630x over previous
//
#include <hip/hip_runtime.h>

// 2-layer GCN, rank-2 factorization + 2-level (dst,src)-range bucketing + LDS
// aggregation. R11: revert R10's last-block fusion (it serialized node-local
// work to 1 block/range); keep its bscatter wins (no recount, block-scan lofs);
// AGG_BLKS 8->16 (agg grids 200->400 blocks, 39%->78% wave capacity);
// cnt matrix stored chunk-major only and scanned IN PLACE (saves 5.2MB ws).

#define NBMAX 1024
#define NRMAX 32
#define AGG_BLKS 16
#define CHUNK 4096
#define NCHP 640         // max chunks (e <= 2.62M edges)
#define DBITS 12
#define DMASK 4095
#define NOEDGE 0xFFFFFFFFu

// ---------------- block-wide exclusive scan (1024 threads) ----------------

__device__ __forceinline__ int block_scan_excl(int v, int tid, int* wtot /*LDS[17]*/) {
    int lane = tid & 63, w = tid >> 6;
    int inc = v;
#pragma unroll
    for (int d = 1; d < 64; d <<= 1) {
        int u = __shfl_up(inc, d);
        if (lane >= d) inc += u;
    }
    if (lane == 63) wtot[w] = inc;
    __syncthreads();
    if (w == 0) {
        int t = (lane < 16) ? wtot[lane] : 0;
#pragma unroll
        for (int d = 1; d < 16; d <<= 1) {
            int u = __shfl_up(t, d);
            if (lane >= d) t += u;
        }
        if (lane < 16) wtot[lane] = t;
        if (lane == 15) wtot[16] = t;   // grand total
    }
    __syncthreads();
    int base = (w > 0) ? wtot[w - 1] : 0;
    return base + inc - v;   // exclusive
}

// ---------------- node-local kernels ----------------

__global__ void k_px(const float2* __restrict__ x, const int* __restrict__ pdeg,
                     float* __restrict__ dinv, float2* __restrict__ px, int n) {
    int i = blockIdx.x * blockDim.x + threadIdx.x;
    if (i >= n) return;
    int deg = 1;  // self-loop
#pragma unroll
    for (int b = 0; b < AGG_BLKS; ++b) deg += pdeg[b * n + i];
    float d = rsqrtf((float)deg);
    dinv[i] = d;
    float2 xv = x[i];
    px[i] = make_float2(d * xv.x, d * xv.y);
}

__global__ void k_node(const float2* __restrict__ px, const float2* __restrict__ pP,
                       const float* __restrict__ dinv,
                       const float* __restrict__ W1, const float* __restrict__ b1,
                       const float* __restrict__ W2, float* __restrict__ s, int n) {
    int i = blockIdx.x * blockDim.x + threadIdx.x;
    if (i >= n) return;
    float2 v = px[i];
    float ax = v.x, ay = v.y;
#pragma unroll
    for (int b = 0; b < AGG_BLKS; ++b) {
        float2 p = pP[b * n + i];
        ax += p.x; ay += p.y;
    }
    float d = dinv[i];
    float dot = 0.f;
#pragma unroll
    for (int j = 0; j < 32; ++j) {
        float acc = fmaf(ax, W1[j], ay * W1[32 + j]);
        float h = fmaxf(fmaf(d, acc, b1[j]), 0.f);
        dot = fmaf(h, W2[j], dot);
    }
    s[i] = d * dot;
}

__global__ void k_out(const float* __restrict__ s, const float* __restrict__ ps,
                      const float* __restrict__ dinv, const float* __restrict__ b2,
                      float* __restrict__ out, int n) {
    int i = blockIdx.x * blockDim.x + threadIdx.x;
    if (i >= n) return;
    float acc = s[i];  // self-loop
#pragma unroll
    for (int b = 0; b < AGG_BLKS; ++b) acc += ps[b * n + i];
    out[i] = dinv[i] * acc + b2[0];
}

// ---------------- bucketing: count -> scanA -> scanB -> scatter ------------

// per-chunk histogram -> chunk-major cntT[blk][bin] (coalesced row store)
__global__ void k_cnt(const int* __restrict__ src, const int* __restrict__ dst,
                      int* __restrict__ cntT, int e, int NS, int NB) {
    __shared__ int h[NBMAX];
    for (int t = threadIdx.x; t < NB; t += blockDim.x) h[t] = 0;
    __syncthreads();
    int c0 = blockIdx.x * CHUNK, c1 = min(c0 + CHUNK, e);
    int len = c1 - c0, lq = len >> 2;
    const int4* d4 = (const int4*)(dst + c0);
    const int4* s4 = (const int4*)(src + c0);
    for (int j = threadIdx.x; j < lq; j += blockDim.x) {
        int4 dv = d4[j], sv = s4[j];
        atomicAdd(&h[(dv.x >> DBITS) * NS + (sv.x >> DBITS)], 1);
        atomicAdd(&h[(dv.y >> DBITS) * NS + (sv.y >> DBITS)], 1);
        atomicAdd(&h[(dv.z >> DBITS) * NS + (sv.z >> DBITS)], 1);
        atomicAdd(&h[(dv.w >> DBITS) * NS + (sv.w >> DBITS)], 1);
    }
    if (threadIdx.x == 0)
        for (int i = lq * 4; i < len; ++i)
            atomicAdd(&h[(dst[c0 + i] >> DBITS) * NS + (src[c0 + i] >> DBITS)], 1);
    __syncthreads();
    for (int t = threadIdx.x; t < NB; t += blockDim.x)
        cntT[blockIdx.x * NBMAX + t] = h[t];
}

// one block PER BIN: IN-PLACE exclusive scan of the bin's column of cntT
__global__ __launch_bounds__(1024)
void k_scanA(int* __restrict__ cntT, int* __restrict__ tot, int NCH) {
    __shared__ int wtot[17];
    int bin = blockIdx.x, tid = threadIdx.x;
    int v = (tid < NCH) ? cntT[tid * NBMAX + bin] : 0;
    int ex = block_scan_excl(v, tid, wtot);
    if (tid < NCH) cntT[tid * NBMAX + bin] = ex;   // counts -> exclusive offsets
    if (tid == 0) tot[bin] = wtot[16];
}

// one block: scan padded bin totals -> gbin, region table, sentinel fill
__global__ __launch_bounds__(1024)
void k_scanB(const int* __restrict__ tot, int* __restrict__ gbin,
             int* __restrict__ rbase, int* __restrict__ rlenp,
             unsigned* __restrict__ packed, int NB, int NS) {
    __shared__ int wtot[17];
    int tid = threadIdx.x;
    int t = (tid < NB) ? tot[tid] : 0;
    int p = (t + 3) & ~3;
    int gb = block_scan_excl(p, tid, wtot);
    int totalp = wtot[16];
    if (tid < NB) {
        gbin[tid] = gb;
        for (int k = t; k < p; ++k) packed[gb + k] = NOEDGE;  // pad sentinels
    }
    __syncthreads();
    if (tid < NB && (tid % NS) == 0) {
        int r = tid / NS;
        rbase[r] = gb;
        int nxt = (tid + NS < NB) ? gbin[tid + NS] : totalp;
        rlenp[r] = nxt - gb;   // multiple of 4
    }
}

// LDS counting-sort per chunk; h recovered from ofs-row diffs (no recount);
// lofs via block-scan; sorted-order flush via dest array.
__global__ __launch_bounds__(1024)
void k_bscatter(const int* __restrict__ src, const int* __restrict__ dst,
                const int* __restrict__ ofsT, const int* __restrict__ tot,
                const int* __restrict__ gbin, unsigned* __restrict__ packed,
                int e, int NS, int NB, int NCH) {
    __shared__ int curx[NBMAX], gba[NBMAX];   // 8 KB
    __shared__ unsigned sbuf[CHUNK];          // 16 KB
    __shared__ int dest[CHUNK];               // 16 KB
    __shared__ int wtot[17];
    int blk = blockIdx.x, tid = threadIdx.x;
    int c0 = blk * CHUNK, c1 = min(c0 + CHUNK, e);
    int len = c1 - c0, lq = len >> 2;
    int cur = 0, hv = 0;
    if (tid < NB) {
        cur = ofsT[blk * NBMAX + tid];                                   // coalesced
        int nxt = (blk + 1 < NCH) ? ofsT[(blk + 1) * NBMAX + tid] : tot[tid];
        hv = nxt - cur;
    }
    int lo = block_scan_excl(hv, tid, wtot);
    if (tid < NB) {
        curx[tid] = lo;
        gba[tid] = gbin[tid] + cur - lo;   // dest = gba[b] + slot
    }
    __syncthreads();
    const int4* d4 = (const int4*)(dst + c0);
    const int4* s4 = (const int4*)(src + c0);
    for (int j = tid; j < lq; j += blockDim.x) {
        int4 dv = d4[j], sv = s4[j];
        {
            int b = (dv.x >> DBITS) * NS + (sv.x >> DBITS);
            int sl = atomicAdd(&curx[b], 1);
            sbuf[sl] = ((unsigned)sv.x << DBITS) | (unsigned)(dv.x & DMASK);
            dest[sl] = gba[b] + sl;
        }
        {
            int b = (dv.y >> DBITS) * NS + (sv.y >> DBITS);
            int sl = atomicAdd(&curx[b], 1);
            sbuf[sl] = ((unsigned)sv.y << DBITS) | (unsigned)(dv.y & DMASK);
            dest[sl] = gba[b] + sl;
        }
        {
            int b = (dv.z >> DBITS) * NS + (sv.z >> DBITS);
            int sl = atomicAdd(&curx[b], 1);
            sbuf[sl] = ((unsigned)sv.z << DBITS) | (unsigned)(dv.z & DMASK);
            dest[sl] = gba[b] + sl;
        }
        {
            int b = (dv.w >> DBITS) * NS + (sv.w >> DBITS);
            int sl = atomicAdd(&curx[b], 1);
            sbuf[sl] = ((unsigned)sv.w << DBITS) | (unsigned)(dv.w & DMASK);
            dest[sl] = gba[b] + sl;
        }
    }
    if (tid == 0)
        for (int i = lq * 4; i < len; ++i) {
            int d = dst[c0 + i], sx = src[c0 + i];
            int b = (d >> DBITS) * NS + (sx >> DBITS);
            int sl = atomicAdd(&curx[b], 1);
            sbuf[sl] = ((unsigned)sx << DBITS) | (unsigned)(d & DMASK);
            dest[sl] = gba[b] + sl;
        }
    __syncthreads();
    for (int t = tid; t < len; t += blockDim.x)
        packed[dest[t]] = sbuf[t];
}

// ---------------- LDS aggregations -> partials (no global atomics) ----------

__global__ __launch_bounds__(1024, 8)
void k_deg(const unsigned* __restrict__ packed, const int* __restrict__ rbase,
           const int* __restrict__ rlenp, int* __restrict__ pdeg, int n) {
    __shared__ int acc[DMASK + 1];   // 16 KB
    int r = blockIdx.y, b = blockIdx.x;
    int rs_r = min(DMASK + 1, n - (r << DBITS));
    for (int t = threadIdx.x; t < rs_r; t += blockDim.x) acc[t] = 0;
    __syncthreads();
    int base = rbase[r], q = rlenp[r] >> 2;
    int qper = (q + gridDim.x - 1) / gridDim.x;
    int qlo = b * qper, qhi = min(qlo + qper, q);
    const uint4* p4 = (const uint4*)(packed + base);
    for (int j = qlo + threadIdx.x; j < qhi; j += blockDim.x) {
        uint4 v = p4[j];
        if (v.x != NOEDGE) atomicAdd(&acc[v.x & DMASK], 1);
        if (v.y != NOEDGE) atomicAdd(&acc[v.y & DMASK], 1);
        if (v.z != NOEDGE) atomicAdd(&acc[v.z & DMASK], 1);
        if (v.w != NOEDGE) atomicAdd(&acc[v.w & DMASK], 1);
    }
    __syncthreads();
    int nb = b * n + (r << DBITS);
    for (int t = threadIdx.x; t < rs_r; t += blockDim.x) pdeg[nb + t] = acc[t];
}

__global__ __launch_bounds__(1024, 8)
void k_agg1(const unsigned* __restrict__ packed, const int* __restrict__ rbase,
            const int* __restrict__ rlenp, const float2* __restrict__ px,
            float2* __restrict__ pP, int n) {
    __shared__ float acc[2 * (DMASK + 1)];   // 32 KB
    int r = blockIdx.y, b = blockIdx.x;
    int rs_r = min(DMASK + 1, n - (r << DBITS));
    for (int t = threadIdx.x; t < 2 * rs_r; t += blockDim.x) acc[t] = 0.f;
    __syncthreads();
    int base = rbase[r], q = rlenp[r] >> 2;
    int qper = (q + gridDim.x - 1) / gridDim.x;
    int qlo = b * qper, qhi = min(qlo + qper, q);
    const uint4* p4 = (const uint4*)(packed + base);
    int nm1 = n - 1;
    for (int j = qlo + threadIdx.x; j < qhi; j += blockDim.x) {
        uint4 v = p4[j];
        int i0 = min((int)(v.x >> DBITS), nm1);   // sentinel-safe clamp
        int i1 = min((int)(v.y >> DBITS), nm1);
        int i2 = min((int)(v.z >> DBITS), nm1);
        int i3 = min((int)(v.w >> DBITS), nm1);
        float2 g0 = px[i0], g1 = px[i1], g2 = px[i2], g3 = px[i3];
        if (v.x != NOEDGE) { int d0 = (v.x & DMASK) * 2; atomicAdd(&acc[d0], g0.x); atomicAdd(&acc[d0 + 1], g0.y); }
        if (v.y != NOEDGE) { int d1 = (v.y & DMASK) * 2; atomicAdd(&acc[d1], g1.x); atomicAdd(&acc[d1 + 1], g1.y); }
        if (v.z != NOEDGE) { int d2 = (v.z & DMASK) * 2; atomicAdd(&acc[d2], g2.x); atomicAdd(&acc[d2 + 1], g2.y); }
        if (v.w != NOEDGE) { int d3 = (v.w & DMASK) * 2; atomicAdd(&acc[d3], g3.x); atomicAdd(&acc[d3 + 1], g3.y); }
    }
    __syncthreads();
    int nb = b * n + (r << DBITS);
    for (int t = threadIdx.x; t < rs_r; t += blockDim.x)
        pP[nb + t] = make_float2(acc[2 * t], acc[2 * t + 1]);
}

__global__ __launch_bounds__(1024, 8)
void k_agg2(const unsigned* __restrict__ packed, const int* __restrict__ rbase,
            const int* __restrict__ rlenp, const float* __restrict__ s,
            float* __restrict__ ps, int n) {
    __shared__ float acc[DMASK + 1];   // 16 KB
    int r = blockIdx.y, b = blockIdx.x;
    int rs_r = min(DMASK + 1, n - (r << DBITS));
    for (int t = threadIdx.x; t < rs_r; t += blockDim.x) acc[t] = 0.f;
    __syncthreads();
    int base = rbase[r], q = rlenp[r] >> 2;
    int qper = (q + gridDim.x - 1) / gridDim.x;
    int qlo = b * qper, qhi = min(qlo + qper, q);
    const uint4* p4 = (const uint4*)(packed + base);
    int nm1 = n - 1;
    for (int j = qlo + threadIdx.x; j < qhi; j += blockDim.x) {
        uint4 v = p4[j];
        int i0 = min((int)(v.x >> DBITS), nm1);
        int i1 = min((int)(v.y >> DBITS), nm1);
        int i2 = min((int)(v.z >> DBITS), nm1);
        int i3 = min((int)(v.w >> DBITS), nm1);
        float g0 = s[i0], g1 = s[i1], g2 = s[i2], g3 = s[i3];
        if (v.x != NOEDGE) atomicAdd(&acc[v.x & DMASK], g0);
        if (v.y != NOEDGE) atomicAdd(&acc[v.y & DMASK], g1);
        if (v.z != NOEDGE) atomicAdd(&acc[v.z & DMASK], g2);
        if (v.w != NOEDGE) atomicAdd(&acc[v.w & DMASK], g3);
    }
    __syncthreads();
    int nb = b * n + (r << DBITS);
    for (int t = threadIdx.x; t < rs_r; t += blockDim.x) ps[nb + t] = acc[t];
}

// ---------------- fallback path (round-2 style) ----------------

__global__ void f_zero(int* __restrict__ ideg, float2* __restrict__ P, int n) {
    int i = blockIdx.x * blockDim.x + threadIdx.x;
    if (i < n) { ideg[i] = 0; P[i] = make_float2(0.f, 0.f); }
}
__global__ void f_count(const int* __restrict__ dst, int* __restrict__ ideg, int e) {
    int i = blockIdx.x * blockDim.x + threadIdx.x;
    if (i < e) atomicAdd(&ideg[dst[i]], 1);
}
__global__ void f_px(const float2* __restrict__ x, const int* __restrict__ ideg,
                     float* __restrict__ dinv, float2* __restrict__ px, int n) {
    int i = blockIdx.x * blockDim.x + threadIdx.x;
    if (i >= n) return;
    float d = rsqrtf((float)(1 + ideg[i]));
    dinv[i] = d;
    float2 xv = x[i];
    px[i] = make_float2(d * xv.x, d * xv.y);
}
__global__ void f_scatter_px(const int* __restrict__ src, const int* __restrict__ dst,
                             const float2* __restrict__ px, float* __restrict__ Pf, int e) {
    int i = blockIdx.x * blockDim.x + threadIdx.x;
    if (i >= e) return;
    int sidx = src[i], d = dst[i];
    float2 v = px[sidx];
    atomicAdd(&Pf[2 * d], v.x);
    atomicAdd(&Pf[2 * d + 1], v.y);
}
__global__ void f_node(const float2* __restrict__ px, const float2* __restrict__ P,
                       const float* __restrict__ dinv,
                       const float* __restrict__ W1, const float* __restrict__ b1,
                       const float* __restrict__ W2,
                       float* __restrict__ s, float* __restrict__ S, int n) {
    int i = blockIdx.x * blockDim.x + threadIdx.x;
    if (i >= n) return;
    float d = dinv[i];
    float2 v = px[i], p = P[i];
    float ax = v.x + p.x, ay = v.y + p.y;
    float dot = 0.f;
#pragma unroll
    for (int j = 0; j < 32; ++j) {
        float acc = fmaf(ax, W1[j], ay * W1[32 + j]);
        float h = fmaxf(fmaf(d, acc, b1[j]), 0.f);
        dot = fmaf(h, W2[j], dot);
    }
    float sv = d * dot;
    s[i] = sv;
    S[i] = sv;
}
__global__ void f_scatter_s(const int* __restrict__ src, const int* __restrict__ dst,
                            const float* __restrict__ s, float* __restrict__ S, int e) {
    int i = blockIdx.x * blockDim.x + threadIdx.x;
    if (i < e) atomicAdd(&S[dst[i]], s[src[i]]);
}
__global__ void f_out(const float* __restrict__ S, const float* __restrict__ dinv,
                      const float* __restrict__ b2, float* __restrict__ out, int n) {
    int i = blockIdx.x * blockDim.x + threadIdx.x;
    if (i < n) out[i] = dinv[i] * S[i] + b2[0];
}

// ---------------- launch ----------------

extern "C" void kernel_launch(void* const* d_in, const int* in_sizes, int n_in,
                              void* d_out, int out_size, void* d_ws, size_t ws_size,
                              hipStream_t stream) {
    const float* x  = (const float*)d_in[0];
    const int*   ei = (const int*)d_in[1];
    const float* W1 = (const float*)d_in[2];
    const float* b1 = (const float*)d_in[3];
    const float* W2 = (const float*)d_in[4];
    const float* b2 = (const float*)d_in[5];
    float* out = (float*)d_out;

    int n = in_sizes[0] / 2;   // 100000
    int e = in_sizes[1] / 2;   // 2560000
    const int* src = ei;
    const int* dst = ei + e;
    int NR  = (n + DMASK) >> DBITS;          // 25
    int NS  = NR;                            // src ranges (same granularity)
    int NB  = NR * NS;                       // 625 bins
    int NCH = (e + CHUNK - 1) / CHUNK;       // 625 chunks

    char* ws = (char*)d_ws;
    auto align = [](size_t v) { return (v + 255) & ~(size_t)255; };
    size_t off = 0;
    float*  dinv = (float*) (ws + off); off = align(off + (size_t)n * 4);
    float2* px   = (float2*)(ws + off); off = align(off + (size_t)n * 8);
    float*  s    = (float*) (ws + off); off = align(off + (size_t)n * 4);
    int*    pdeg = (int*)   (ws + off); off = align(off + (size_t)AGG_BLKS * n * 4);
    float2* pP   = (float2*)(ws + off); off = align(off + (size_t)AGG_BLKS * n * 8);
    float*  ps   = (float*) (ws + off); off = align(off + (size_t)AGG_BLKS * n * 4);
    int*    rbase = (int*)(ws + off); off = align(off + NRMAX * 4);
    int*    rlenp = (int*)(ws + off); off = align(off + NRMAX * 4);
    int*    gbin  = (int*)(ws + off); off = align(off + NBMAX * 4);
    int*    tot   = (int*)(ws + off); off = align(off + NBMAX * 4);
    int*    cntT  = (int*)(ws + off); off = align(off + (size_t)NCHP * NBMAX * 4);
    unsigned* packed = (unsigned*)(ws + off);
    size_t need = off + (size_t)(e + 4 * NBMAX) * 4;

    const int B = 256;
    int gn = (n + B - 1) / B, ge = (e + B - 1) / B;

    bool fast = (need <= ws_size) && (NB <= NBMAX) && (NCH <= NCHP) && (NR <= NRMAX);

    if (fast) {
        dim3 ag(AGG_BLKS, NR);
        k_cnt     <<<NCH, B, 0, stream>>>(src, dst, cntT, e, NS, NB);
        k_scanA   <<<NB, 1024, 0, stream>>>(cntT, tot, NCH);
        k_scanB   <<<1, 1024, 0, stream>>>(tot, gbin, rbase, rlenp, packed, NB, NS);
        k_bscatter<<<NCH, 1024, 0, stream>>>(src, dst, cntT, tot, gbin, packed, e, NS, NB, NCH);
        k_deg     <<<ag, 1024, 0, stream>>>(packed, rbase, rlenp, pdeg, n);
        k_px      <<<gn, B, 0, stream>>>((const float2*)x, pdeg, dinv, px, n);
        k_agg1    <<<ag, 1024, 0, stream>>>(packed, rbase, rlenp, px, pP, n);
        k_node    <<<gn, B, 0, stream>>>(px, pP, dinv, W1, b1, W2, s, n);
        k_agg2    <<<ag, 1024, 0, stream>>>(packed, rbase, rlenp, s, ps, n);
        k_out     <<<gn, B, 0, stream>>>(s, ps, dinv, b2, out, n);
    } else {
        int*   ideg = pdeg;
        float2* P   = pP;
        float* S    = ps;
        f_zero      <<<gn, B, 0, stream>>>(ideg, P, n);
        f_count     <<<ge, B, 0, stream>>>(dst, ideg, e);
        f_px        <<<gn, B, 0, stream>>>((const float2*)x, ideg, dinv, px, n);
        f_scatter_px<<<ge, B, 0, stream>>>(src, dst, px, (float*)P, e);
        f_node      <<<gn, B, 0, stream>>>(px, P, dinv, W1, b1, W2, s, S, n);
        f_scatter_s <<<ge, B, 0, stream>>>(src, dst, s, S, e);
        f_out       <<<gn, B, 0, stream>>>(S, dinv, b2, out, n);
    }
}